// Round 2
// baseline (2468.958 us; speedup 1.0000x reference)
//
#include <hip/hip_runtime.h>

#define BB 4096      // batch
#define CC 512       // features
#define TT_ 4096     // trees
#define NN 1023      // internal nodes
#define NL 1024      // leaves
#define DEPTH 10
#define SP 32        // samples per block (panel)
#define TG 8         // trees staged per group
#define GROUPS 16    // groups per block -> 128 trees per tree-block
#define TREES_PER_BLOCK (TG * GROUPS)   // 128
#define NPANELS (BB / SP)               // 128
#define NTREEBLOCKS (TT_ / TREES_PER_BLOCK) // 32

// LDS layout (128 KiB exactly):
//   xs      [512][32] f32   @ 0       (65536 B)  x panel, transposed
//   thr_lds [8][1024] f32   @ 65536   (32768 B)
//   ord_lds [8][1024] u16   @ 98304   (16384 B)
//   res     [32][128] f32   @ 114688  (16384 B)  output tile
#define LDS_BYTES 131072

__global__ __launch_bounds__(256, 1)
void rhf_kernel(const float* __restrict__ x,
                const float* __restrict__ thr_g,
                const int*   __restrict__ ord_g,
                const float* __restrict__ wts,
                float* __restrict__ out) {
    extern __shared__ char smem[];
    float*          xs      = (float*)(smem);
    float*          thr_lds = (float*)(smem + 65536);
    unsigned short* ord_lds = (unsigned short*)(smem + 65536 + 32768);
    float*          res     = (float*)(smem + 65536 + 32768 + 16384);

    const int tid   = threadIdx.x;
    const int s     = tid & 31;     // sample within panel
    const int slot  = tid >> 5;     // tree slot 0..7
    const int panel = blockIdx.x & (NPANELS - 1);
    const int tb    = blockIdx.x >> 7;

    // ---- stage x panel, transposed: xs[c*32 + r] = x[panel*32 + r][c] ----
    const float* xbase = x + (size_t)panel * SP * CC;
    #pragma unroll
    for (int k = 0; k < (SP * CC) / 256; ++k) {
        int idx = k * 256 + tid;      // 0..16383
        int r   = idx >> 9;           // sample row 0..31
        int c   = idx & 511;          // feature
        xs[(c << 5) + r] = xbase[r * CC + c];   // global read coalesced
    }
    __syncthreads();

    for (int g = 0; g < GROUPS; ++g) {
        const int tbase = tb * TREES_PER_BLOCK + g * TG;

        // ---- stage 8 trees: thresholds f32 + ordinals u16 ----
        for (int q = 0; q < TG; ++q) {
            const float* trow = thr_g + (size_t)(tbase + q) * NN;
            const int*   orow = ord_g + (size_t)(tbase + q) * NN;
            #pragma unroll
            for (int k = 0; k < 4; ++k) {
                int j = k * 256 + tid;
                if (j < NN) {
                    thr_lds[(q << 10) + j] = trow[j];
                    ord_lds[(q << 10) + j] = (unsigned short)orow[j];
                }
            }
        }
        __syncthreads();

        // ---- traverse: thread = (sample s, tree slot) ----
        const int t = tbase + slot;
        const int nb = slot << 10;   // node-data base for this slot
        float minm = __builtin_inff();
        int   node = 0;
        float thv = thr_lds[nb];
        int   orv = ord_lds[nb];
        #pragma unroll
        for (int d = 0; d < DEPTH; ++d) {
            float thL = 0.f, thR = 0.f;
            int   orL = 0,   orR = 0;
            if (d < DEPTH - 1) {
                int cb = 2 * node + 1;           // children known before compare
                thL = thr_lds[nb + cb];
                thR = thr_lds[nb + cb + 1];
                orL = ord_lds[nb + cb];
                orR = ord_lds[nb + cb + 1];
            }
            float feat = xs[(orv << 5) + s];     // conflict-free gather
            float m    = feat - thv;
            bool  take = fabsf(m) < fabsf(minm);
            minm = take ? m : minm;
            int right = (m > 0.0f) ? 1 : 0;
            node = 2 * node + 1 + right;
            if (d < DEPTH - 1) {
                thv = right ? thR : thL;
                orv = right ? orR : orL;
            }
        }
        const int leaf = node - NN;
        float w = wts[(size_t)t * NL + leaf];
        res[(s << 7) + (g << 3) + slot] = fabsf(minm) * w;
        __syncthreads();   // protect thr/ord_lds (next group) and res (final read)
    }

    // ---- coalesced output: out[(panel*32+r)*T + tb*128 + c] ----
    float* obase = out + (size_t)panel * SP * TT_ + (size_t)tb * TREES_PER_BLOCK;
    #pragma unroll
    for (int k = 0; k < (SP * TREES_PER_BLOCK) / 256; ++k) {
        int idx = k * 256 + tid;
        int r   = idx >> 7;
        int c   = idx & 127;
        obase[(size_t)r * TT_ + c] = res[(r << 7) + c];
    }
}

extern "C" void kernel_launch(void* const* d_in, const int* in_sizes, int n_in,
                              void* d_out, int out_size, void* d_ws, size_t ws_size,
                              hipStream_t stream) {
    const float* x    = (const float*)d_in[0];
    const float* thr  = (const float*)d_in[1];
    const int*   ordv = (const int*)d_in[2];
    const float* wts  = (const float*)d_in[3];
    float*       out  = (float*)d_out;

    hipFuncSetAttribute((const void*)rhf_kernel,
                        hipFuncAttributeMaxDynamicSharedMemorySize, LDS_BYTES);

    dim3 grid(NPANELS * NTREEBLOCKS);   // 4096 blocks
    rhf_kernel<<<grid, 256, LDS_BYTES, stream>>>(x, thr, ordv, wts, out);
}

// Round 3
// 1308.905 us; speedup vs baseline: 1.8863x; 1.8863x over previous
//
#include <hip/hip_runtime.h>

#define BB 4096      // batch
#define CC 512       // features
#define TT_ 4096     // trees
#define NN 1023      // internal nodes
#define NL 1024      // leaves
#define DEPTH 10
#define SP 32        // samples per block (panel)
#define TG 8         // trees staged per group
#define GROUPS 16    // groups per block -> 128 trees per tree-block
#define TREES_PER_BLOCK (TG * GROUPS)   // 128
#define NPANELS (BB / SP)               // 128
#define NTREEBLOCKS (TT_ / TREES_PER_BLOCK) // 32
#define GFLAT (TG * NN)                 // 8184 nodes per group

// LDS layout (128 KiB exactly):
//   xs       [512][32] f32   @ 0       (65536 B)  x panel, transposed
//   thr_flat [8184]    f32   @ 65536   (32736 -> pad 32768 B)
//   ord_flat [8184]    u16   @ 98304   (16368 -> pad 16384 B)
//   res      [32][128] f32   @ 114688  (16384 B)  output tile (col-swizzled by +row)
#define LDS_BYTES 131072

__global__ __launch_bounds__(256, 1)
void rhf_kernel(const float* __restrict__ x,
                const float* __restrict__ thr_g,
                const int*   __restrict__ ord_g,
                const float* __restrict__ wts,
                float* __restrict__ out) {
    extern __shared__ char smem[];
    float*          xs       = (float*)(smem);
    float*          thr_flat = (float*)(smem + 65536);
    unsigned short* ord_flat = (unsigned short*)(smem + 98304);
    float*          res      = (float*)(smem + 114688);

    const int tid   = threadIdx.x;
    const int s     = tid & 31;     // sample within panel
    const int slot  = tid >> 5;     // tree slot 0..7
    const int panel = blockIdx.x & (NPANELS - 1);
    const int tb    = blockIdx.x >> 7;

    // ---- stage x panel, transposed: xs[c*32 + r] = x[panel*32 + r][c] ----
    const float* xbase = x + (size_t)panel * SP * CC;
    #pragma unroll
    for (int k = 0; k < (SP * CC) / 256; ++k) {
        int idx = k * 256 + tid;      // 0..16383
        int r   = idx >> 9;           // sample row 0..31
        int c   = idx & 511;          // feature
        xs[(c << 5) + r] = xbase[r * CC + c];   // global read coalesced
    }
    // visibility of xs covered by the barriers inside the group loop (before any traversal)

    // ---- register-prefetch pipeline state: one group's tree data (8 trees) ----
    // group flat region: 8184 consecutive f32 (thr) / i32 (ord); 16B-aligned
    // per thread: 8 x float4 + 8 x int4 (i = k*256+tid, guarded i < 2046)
    float4 pthr[8];
    int4   pord[8];
    const float* gthr = thr_g + (size_t)tb * TREES_PER_BLOCK * NN;
    const int*   gord = ord_g + (size_t)tb * TREES_PER_BLOCK * NN;

    auto prefetch = [&](int g) {
        const float4* pt = (const float4*)(gthr + (size_t)g * GFLAT);
        const int4*   po = (const int4*)(gord + (size_t)g * GFLAT);
        #pragma unroll
        for (int k = 0; k < 8; ++k) {
            int i = k * 256 + tid;        // dword4 index, covers 8192 >= 8184
            if (i < GFLAT / 4) {          // 2046
                pthr[k] = pt[i];
                pord[k] = po[i];
            }
        }
    };

    auto commit = [&]() {
        #pragma unroll
        for (int k = 0; k < 8; ++k) {
            int i = k * 256 + tid;
            if (i < GFLAT / 4) {
                ((float4*)thr_flat)[i] = pthr[k];
                unsigned int a = ((unsigned)pord[k].x & 0xffffu) | (((unsigned)pord[k].y & 0xffffu) << 16);
                unsigned int b = ((unsigned)pord[k].z & 0xffffu) | (((unsigned)pord[k].w & 0xffffu) << 16);
                ((uint2*)ord_flat)[i] = make_uint2(a, b);
            }
        }
    };

    prefetch(0);

    for (int g = 0; g < GROUPS; ++g) {
        __syncthreads();   // (A) drains prefetch vmcnt (wanted: commit consumes regs now)
                           //     + all waves done reading previous group's LDS
        commit();
        __syncthreads();   // (B) staged trees visible to all waves
        if (g + 1 < GROUPS) prefetch(g + 1);   // issued now, drained at next (A): hides under traversal

        // ---- traverse: thread = (sample s, tree slot), 8 trees in flight per wave ----
        const int t  = tb * TREES_PER_BLOCK + g * TG + slot;
        const int nb = slot * NN;            // flat row base (stride 1023 spreads banks per slot)
        float minm = __builtin_inff();
        int   node = 0;
        float thv = thr_flat[nb];
        int   orv = ord_flat[nb];
        #pragma unroll
        for (int d = 0; d < DEPTH; ++d) {
            float thL = 0.f, thR = 0.f;
            int   orL = 0,   orR = 0;
            if (d < DEPTH - 1) {
                int cb = 2 * node + 1;       // children known before compare resolves
                thL = thr_flat[nb + cb];
                thR = thr_flat[nb + cb + 1];
                orL = ord_flat[nb + cb];
                orR = ord_flat[nb + cb + 1];
            }
            float feat = xs[(orv << 5) + s]; // bank = s: conflict-free gather
            float m    = feat - thv;
            bool  take = fabsf(m) < fabsf(minm);
            minm = take ? m : minm;
            int right = (m > 0.0f) ? 1 : 0;
            node = 2 * node + 1 + right;
            if (d < DEPTH - 1) {
                thv = right ? thR : thL;
                orv = right ? orR : orL;
            }
        }
        const int leaf = node - NN;
        float w = wts[(size_t)t * NL + leaf];
        // col-swizzled by +s to avoid a 32-way bank conflict on this write
        res[(s << 7) + ((g * TG + slot + s) & 127)] = fabsf(minm) * w;
    }
    __syncthreads();   // res complete

    // ---- coalesced output: out[(panel*32+r)*T + tb*128 + c] ----
    float* obase = out + (size_t)panel * SP * TT_ + (size_t)tb * TREES_PER_BLOCK;
    #pragma unroll
    for (int k = 0; k < (SP * TREES_PER_BLOCK) / 256; ++k) {
        int idx = k * 256 + tid;
        int r   = idx >> 7;
        int c   = idx & 127;
        obase[(size_t)r * TT_ + c] = res[(r << 7) + ((c + r) & 127)];
    }
}

extern "C" void kernel_launch(void* const* d_in, const int* in_sizes, int n_in,
                              void* d_out, int out_size, void* d_ws, size_t ws_size,
                              hipStream_t stream) {
    const float* x    = (const float*)d_in[0];
    const float* thr  = (const float*)d_in[1];
    const int*   ordv = (const int*)d_in[2];
    const float* wts  = (const float*)d_in[3];
    float*       out  = (float*)d_out;

    hipFuncSetAttribute((const void*)rhf_kernel,
                        hipFuncAttributeMaxDynamicSharedMemorySize, LDS_BYTES);

    dim3 grid(NPANELS * NTREEBLOCKS);   // 4096 blocks
    rhf_kernel<<<grid, 256, LDS_BYTES, stream>>>(x, thr, ordv, wts, out);
}

// Round 4
// 541.288 us; speedup vs baseline: 4.5613x; 2.4181x over previous
//
#include <hip/hip_runtime.h>
#include <hip/hip_fp16.h>

#define BB 4096      // batch
#define CC 512       // features
#define TT_ 4096     // trees
#define NN 1023      // internal nodes
#define NL 1024      // leaves
#define DEPTH 10
#define SP 32        // samples per block (panel)
#define TG 16        // trees staged per group
#define GROUPS 8     // groups per block -> 128 trees per tree-block
#define TREES_PER_BLOCK (TG * GROUPS)   // 128
#define NPANELS (BB / SP)               // 128
#define NTREEBLOCKS (TT_ / TREES_PER_BLOCK) // 32
#define NTHREADS 512

// LDS layout (144 KiB):
//   xs  [512][32] f32        @ 0       (65536 B)  x panel, transposed; gather bank = s
//   pk  [16][1024] u32       @ 65536   (65536 B)  packed trees: slot = node+1, slot0 unused
//                                                 pk[slot] = (ord<<16) | f16bits(thr)
//   res [32][128] f32        @ 131072  (16384 B)  output tile, diagonal-swizzled
#define LDS_BYTES 147456

__global__ __launch_bounds__(NTHREADS, 1)
void rhf_kernel(const float* __restrict__ x,
                const float* __restrict__ thr_g,
                const int*   __restrict__ ord_g,
                const float* __restrict__ wts,
                float* __restrict__ out) {
    extern __shared__ char smem[];
    float*        xs  = (float*)(smem);
    unsigned int* pk  = (unsigned int*)(smem + 65536);
    float*        res = (float*)(smem + 131072);

    const int tid  = threadIdx.x;
    const int s    = tid & 31;      // sample within panel (also staging lane u)
    const int slot = tid >> 5;      // tree slot 0..15 (also staging tree q)
    const int panel = blockIdx.x & (NPANELS - 1);
    const int tb    = blockIdx.x >> 7;

    // ---- stage x panel, transposed: xs[c*32 + r] = x[panel*32 + r][c] ----
    const float* xbase = x + (size_t)panel * SP * CC;
    #pragma unroll
    for (int k = 0; k < (SP * CC) / NTHREADS; ++k) {
        int idx = k * NTHREADS + tid;   // 0..16383
        int r   = idx >> 9;
        int c   = idx & 511;
        xs[(c << 5) + r] = xbase[r * CC + c];
    }

    // ---- register prefetch: each 32-thread cohort (q=slot) stages one tree ----
    // nodes j = k*128 + 4*s, k<8  (covers multiples of 4 in [0,1020])
    float4 pthr[8];
    int4   pord[8];
    float  tthr[3];      // tail j==1020: nodes 1020..1022
    int    tord[3];

    auto prefetch = [&](int g) {
        const size_t base = (size_t)(tb * TREES_PER_BLOCK + g * TG + slot) * NN;
        #pragma unroll
        for (int k = 0; k < 8; ++k) {
            int j = k * 128 + 4 * s;
            if (j < 1020) {
                pthr[k] = *(const float4*)(thr_g + base + j);
                pord[k] = *(const int4*)(ord_g + base + j);
            } else {            // j == 1020 only for (k==7, s==31)
                tthr[0] = thr_g[base + 1020]; tord[0] = ord_g[base + 1020];
                tthr[1] = thr_g[base + 1021]; tord[1] = ord_g[base + 1021];
                tthr[2] = thr_g[base + 1022]; tord[2] = ord_g[base + 1022];
            }
        }
    };

    auto pack1 = [](float f, int o) -> unsigned int {
        return ((unsigned int)o << 16) | (unsigned int)__half_as_ushort(__float2half(f));
    };

    auto commit = [&]() {
        unsigned int* pt = pk + (slot << 10);   // this cohort's tree
        #pragma unroll
        for (int k = 0; k < 8; ++k) {
            int j = k * 128 + 4 * s;
            if (j < 1020) {
                pt[1 + j + 0] = pack1(pthr[k].x, pord[k].x);
                pt[1 + j + 1] = pack1(pthr[k].y, pord[k].y);
                pt[1 + j + 2] = pack1(pthr[k].z, pord[k].z);
                pt[1 + j + 3] = pack1(pthr[k].w, pord[k].w);
            } else {
                pt[1 + 1020] = pack1(tthr[0], tord[0]);
                pt[1 + 1021] = pack1(tthr[1], tord[1]);
                pt[1 + 1022] = pack1(tthr[2], tord[2]);
            }
        }
    };

    prefetch(0);
    __builtin_amdgcn_sched_barrier(0);   // pin loads: do NOT sink past this point

    for (int g = 0; g < GROUPS; ++g) {
        __syncthreads();   // (A) xs/previous-group reads done; prefetch vmcnt drains here
        commit();
        __syncthreads();   // (B) packed trees visible
        if (g + 1 < GROUPS) prefetch(g + 1);
        __builtin_amdgcn_sched_barrier(0);   // keep next prefetch issued BEFORE traversal

        // ---- traverse: thread = (sample s, tree slot) ----
        const int t = tb * TREES_PER_BLOCK + g * TG + slot;
        const unsigned int* pkt = pk + (slot << 10);
        float minm = __builtin_inff();
        int   sl   = 1;                       // slot = node+1; root at 1
        unsigned int cur = pkt[1];
        #pragma unroll
        for (int d = 0; d < DEPTH; ++d) {
            uint2 ch;
            if (d < DEPTH - 1) {
                ch = *(const uint2*)(pkt + 2 * sl);   // children (2sl, 2sl+1), 8B-aligned
            }
            float thv = __half2float(__ushort_as_half((unsigned short)(cur & 0xffffu)));
            int   orv = (int)(cur >> 16);
            float feat = xs[(orv << 5) + s];          // bank = s: conflict-free
            float m    = feat - thv;
            bool  take = fabsf(m) < fabsf(minm);
            minm = take ? m : minm;
            int right = (m > 0.0f) ? 1 : 0;
            sl = 2 * sl + right;
            if (d < DEPTH - 1) {
                cur = right ? ch.y : ch.x;
            }
        }
        const int leaf = sl - NL;
        float w = wts[(size_t)t * NL + leaf];
        int col = g * TG + slot;
        res[(s << 7) + ((col + 4 * s) & 127)] = fabsf(minm) * w;   // diagonal swizzle
    }
    __syncthreads();   // res complete

    // ---- coalesced output ----
    float* obase = out + (size_t)panel * SP * TT_ + (size_t)tb * TREES_PER_BLOCK;
    #pragma unroll
    for (int k = 0; k < (SP * TREES_PER_BLOCK) / NTHREADS; ++k) {
        int idx = k * NTHREADS + tid;
        int r   = idx >> 7;
        int c   = idx & 127;
        obase[(size_t)r * TT_ + c] = res[(r << 7) + ((c + 4 * r) & 127)];
    }
}

extern "C" void kernel_launch(void* const* d_in, const int* in_sizes, int n_in,
                              void* d_out, int out_size, void* d_ws, size_t ws_size,
                              hipStream_t stream) {
    const float* x    = (const float*)d_in[0];
    const float* thr  = (const float*)d_in[1];
    const int*   ordv = (const int*)d_in[2];
    const float* wts  = (const float*)d_in[3];
    float*       out  = (float*)d_out;

    hipFuncSetAttribute((const void*)rhf_kernel,
                        hipFuncAttributeMaxDynamicSharedMemorySize, LDS_BYTES);

    dim3 grid(NPANELS * NTREEBLOCKS);   // 4096 blocks
    rhf_kernel<<<grid, NTHREADS, LDS_BYTES, stream>>>(x, thr, ordv, wts, out);
}

// Round 5
// 197.841 us; speedup vs baseline: 12.4795x; 2.7360x over previous
//
#include <hip/hip_runtime.h>
#include <hip/hip_fp16.h>

#define BB 4096
#define CC 512
#define TT 4096
#define NN 1023
#define NL 1024
#define DEPTH 10

// ===================== pre-kernels (write d_ws) =====================

// pk[t][0]=0; pk[t][1+j] = (ord<<16) | f16bits(thr)   (slot = node+1)
__global__ __launch_bounds__(256) void pack_trees(const float* __restrict__ thr,
                                                  const int* __restrict__ ord,
                                                  unsigned int* __restrict__ pk) {
    int t = blockIdx.x;
    const float* tr = thr + (size_t)t * NN;
    const int*   oo = ord + (size_t)t * NN;
    unsigned int* o = pk + ((size_t)t << 10);
    if (threadIdx.x == 0) o[0] = 0u;
    for (int j = threadIdx.x; j < NN; j += 256)
        o[1 + j] = ((unsigned int)oo[j] << 16) |
                   (unsigned int)__half_as_ushort(__float2half(tr[j]));
}

// xt[c*2048 + b2] = {lo: f16 x[b2][c], hi: f16 x[b2+2048][c]}  (b2 < 2048)
__global__ __launch_bounds__(256) void pack_x(const float* __restrict__ x,
                                              unsigned int* __restrict__ xt) {
    __shared__ float tA[32][33];
    __shared__ float tB[32][33];
    int tx = threadIdx.x & 31, ty = threadIdx.x >> 5;   // 32 x 8
    int b0 = blockIdx.x * 32;      // b2 tile
    int c0 = blockIdx.y * 32;      // c tile
    for (int i = ty; i < 32; i += 8) {
        tA[i][tx] = x[(size_t)(b0 + i) * CC + c0 + tx];
        tB[i][tx] = x[(size_t)(2048 + b0 + i) * CC + c0 + tx];
    }
    __syncthreads();
    for (int i = ty; i < 32; i += 8) {
        int c = c0 + i;
        unsigned int lo = __half_as_ushort(__float2half(tA[tx][i]));
        unsigned int hi = __half_as_ushort(__float2half(tB[tx][i]));
        xt[(size_t)c * 2048 + b0 + tx] = lo | (hi << 16);
    }
}

// ===================== main kernel =====================
// grid 2048 = 64 panels x 32 tree-blocks; 512 threads = 8 waves
// wave w handles ONE tree per group (64 lanes = 64 samples), 16 groups x 8 = 128 trees/block
// LDS (exactly 160 KiB):
//   xs2 u32[512][32] @ 0       (64K)  {f16 x[b], f16 x[b+2048]} ; gather bank = lane&31
//   pk  u32[8][2][1024] @ 64K  (64K)  per-wave double-buffered packed tree
//   res u32[64][128] @ 128K    (32K)  (leaf<<21)|(f32bits(|minm|)>>11), +r col swizzle
#define LDS_BYTES 163840

typedef __attribute__((address_space(1))) const void gv_t;
typedef __attribute__((address_space(3))) void lv_t;

__global__ __launch_bounds__(512, 1)
void rhf_main(const unsigned int* __restrict__ pkg,
              const unsigned int* __restrict__ xt,
              const float* __restrict__ wts,
              float* __restrict__ out) {
    extern __shared__ char smem[];
    unsigned int* xs2 = (unsigned int*)smem;
    unsigned int* pk  = (unsigned int*)(smem + 65536);
    unsigned int* res = (unsigned int*)(smem + 131072);

    const int tid   = threadIdx.x;
    const int lane  = tid & 63;
    const int wv    = tid >> 6;          // 0..7 == tree slot within group
    const int panel = blockIdx.x & 63;
    const int tb    = blockIdx.x >> 6;

    // ---- stage xs2: coalesced uint4; LDS writes conflict-free ----
    {
        const unsigned int* src = xt + (size_t)panel * 32;
        #pragma unroll
        for (int k = 0; k < 8; ++k) {
            int i4 = k * 512 + tid;          // 4096 uint4 = 64KB
            int c  = i4 >> 3;
            int s0 = (i4 & 7) << 2;
            uint4 v = *(const uint4*)(src + (size_t)c * 2048 + s0);
            *(uint4*)(xs2 + (i4 << 2)) = v;  // banks: 64 lanes cover all, 2-way (free)
        }
    }

    // ---- per-wave tree DMA: 4KB = 4 x (64 lanes x 16B) ----
    const char* gbase = (const char*)(pkg + ((size_t)tb * 128) * 1024);
    char* pkw = (char*)(pk + wv * 2048);
    auto dma = [&](int g, int buf) {
        const char* s = gbase + ((size_t)(g * 8 + wv)) * 4096 + lane * 16;
        char* d = pkw + buf * 4096;
        __builtin_amdgcn_global_load_lds((gv_t*)(s),        (lv_t*)(d),        16, 0, 0);
        __builtin_amdgcn_global_load_lds((gv_t*)(s + 1024), (lv_t*)(d + 1024), 16, 0, 0);
        __builtin_amdgcn_global_load_lds((gv_t*)(s + 2048), (lv_t*)(d + 2048), 16, 0, 0);
        __builtin_amdgcn_global_load_lds((gv_t*)(s + 3072), (lv_t*)(d + 3072), 16, 0, 0);
    };

    dma(0, 0);
    __syncthreads();     // xs2 visible to all waves; drains this wave's DMA(0)

    const int r   = lane;                 // sample row 0..63
    const int sfx = lane & 31;            // xs2 column (bank = sfx: conflict-free)
    const int hsh = (lane & 32) >> 1;     // 0 / 16 : which f16 half

    int cur = 0;
    for (int g = 0; g < 16; ++g) {
        if (g < 15) dma(g + 1, cur ^ 1);             // fire-and-forget into alt buffer
        const unsigned int* pkt = pk + wv * 2048 + cur * 1024;
        float amin = __builtin_inff();
        int sl = 1;                                   // slot = node+1, root at 1
        unsigned int nd = pkt[1];
        #pragma unroll
        for (int d = 0; d < DEPTH; ++d) {
            uint2 ch;
            if (d < DEPTH - 1) ch = *(const uint2*)(pkt + 2 * sl);  // 8B-aligned children
            float thv = __half2float(__ushort_as_half((unsigned short)(nd & 0xffffu)));
            int   orv = (int)(nd >> 16);
            unsigned int xw = xs2[(orv << 5) + sfx];                 // bank = sfx
            float feat = __half2float(__ushort_as_half((unsigned short)((xw >> hsh) & 0xffffu)));
            float m = feat - thv;
            amin = fminf(amin, fabsf(m));
            int right = (m > 0.0f) ? 1 : 0;
            sl = 2 * sl + right;
            if (d < DEPTH - 1) nd = right ? ch.y : ch.x;
        }
        int leaf = sl - NL;
        unsigned int p = ((unsigned int)leaf << 21) | (__float_as_uint(amin) >> 11);
        int col = g * 8 + wv;
        res[(r << 7) + ((col + r) & 127)] = p;        // 2-way (free)
        if (g < 15) {
            asm volatile("s_waitcnt vmcnt(0)" ::: "memory");  // own DMA(g+1) landed
            __builtin_amdgcn_sched_barrier(0);
            cur ^= 1;
        }
    }
    __syncthreads();     // all res entries visible

    // ---- output: batched wts gather (16 independent loads) + coalesced stores ----
    #pragma unroll
    for (int k = 0; k < 16; ++k) {
        int idx = k * 512 + tid;
        int rr = idx >> 7;
        int c  = idx & 127;
        unsigned int p = res[(rr << 7) + ((c + rr) & 127)];
        int   leaf = (int)(p >> 21);
        float am   = __uint_as_float((p & 0x1FFFFFu) << 11);
        int   t    = tb * 128 + c;
        float w    = wts[(size_t)t * NL + leaf];
        size_t b = (rr < 32) ? ((size_t)panel * 32 + rr)
                             : ((size_t)2048 + (size_t)panel * 32 + (rr - 32));
        out[b * TT + t] = am * w;
    }
}

// ===================== fallback (round-4, proven 541us) =====================
#define F_SP 32
#define F_TG 16
#define F_GROUPS 8
#define F_TPB (F_TG * F_GROUPS)
#define F_NPANELS (BB / F_SP)
#define F_LDS 147456

__global__ __launch_bounds__(512, 1)
void rhf_fallback(const float* __restrict__ x, const float* __restrict__ thr_g,
                  const int* __restrict__ ord_g, const float* __restrict__ wts,
                  float* __restrict__ out) {
    extern __shared__ char smem[];
    float*        xs  = (float*)(smem);
    unsigned int* pk  = (unsigned int*)(smem + 65536);
    float*        res = (float*)(smem + 131072);
    const int tid = threadIdx.x, s = tid & 31, slot = tid >> 5;
    const int panel = blockIdx.x & (F_NPANELS - 1), tb = blockIdx.x >> 7;
    const float* xbase = x + (size_t)panel * F_SP * CC;
    #pragma unroll
    for (int k = 0; k < (F_SP * CC) / 512; ++k) {
        int idx = k * 512 + tid, r = idx >> 9, c = idx & 511;
        xs[(c << 5) + r] = xbase[r * CC + c];
    }
    float4 pthr[8]; int4 pord[8]; float tthr[3]; int tord[3];
    auto prefetch = [&](int g) {
        const size_t base = (size_t)(tb * F_TPB + g * F_TG + slot) * NN;
        #pragma unroll
        for (int k = 0; k < 8; ++k) {
            int j = k * 128 + 4 * s;
            if (j < 1020) { pthr[k] = *(const float4*)(thr_g + base + j);
                            pord[k] = *(const int4*)(ord_g + base + j); }
            else { tthr[0]=thr_g[base+1020]; tord[0]=ord_g[base+1020];
                   tthr[1]=thr_g[base+1021]; tord[1]=ord_g[base+1021];
                   tthr[2]=thr_g[base+1022]; tord[2]=ord_g[base+1022]; }
        }
    };
    auto pack1 = [](float f, int o) -> unsigned int {
        return ((unsigned int)o << 16) | (unsigned int)__half_as_ushort(__float2half(f));
    };
    auto commit = [&]() {
        unsigned int* pt = pk + (slot << 10);
        #pragma unroll
        for (int k = 0; k < 8; ++k) {
            int j = k * 128 + 4 * s;
            if (j < 1020) {
                pt[1+j+0]=pack1(pthr[k].x,pord[k].x); pt[1+j+1]=pack1(pthr[k].y,pord[k].y);
                pt[1+j+2]=pack1(pthr[k].z,pord[k].z); pt[1+j+3]=pack1(pthr[k].w,pord[k].w);
            } else { pt[1+1020]=pack1(tthr[0],tord[0]); pt[1+1021]=pack1(tthr[1],tord[1]);
                     pt[1+1022]=pack1(tthr[2],tord[2]); }
        }
    };
    prefetch(0);
    __builtin_amdgcn_sched_barrier(0);
    for (int g = 0; g < F_GROUPS; ++g) {
        __syncthreads();
        commit();
        __syncthreads();
        if (g + 1 < F_GROUPS) prefetch(g + 1);
        __builtin_amdgcn_sched_barrier(0);
        const int t = tb * F_TPB + g * F_TG + slot;
        const unsigned int* pkt = pk + (slot << 10);
        float minm = __builtin_inff();
        int sl = 1;
        unsigned int cur = pkt[1];
        #pragma unroll
        for (int d = 0; d < DEPTH; ++d) {
            uint2 ch;
            if (d < DEPTH - 1) ch = *(const uint2*)(pkt + 2 * sl);
            float thv = __half2float(__ushort_as_half((unsigned short)(cur & 0xffffu)));
            int orv = (int)(cur >> 16);
            float feat = xs[(orv << 5) + s];
            float m = feat - thv;
            bool take = fabsf(m) < fabsf(minm);
            minm = take ? m : minm;
            int right = (m > 0.0f) ? 1 : 0;
            sl = 2 * sl + right;
            if (d < DEPTH - 1) cur = right ? ch.y : ch.x;
        }
        int leaf = sl - NL;
        float w = wts[(size_t)t * NL + leaf];
        int col = g * F_TG + slot;
        res[(s << 7) + ((col + s) & 127)] = fabsf(minm) * w;
    }
    __syncthreads();
    float* obase = out + (size_t)panel * F_SP * TT + (size_t)tb * F_TPB;
    #pragma unroll
    for (int k = 0; k < (F_SP * F_TPB) / 512; ++k) {
        int idx = k * 512 + tid, rr = idx >> 7, c = idx & 127;
        obase[(size_t)rr * TT + c] = res[(rr << 7) + ((c + rr) & 127)];
    }
}

// ===================== launch =====================
extern "C" void kernel_launch(void* const* d_in, const int* in_sizes, int n_in,
                              void* d_out, int out_size, void* d_ws, size_t ws_size,
                              hipStream_t stream) {
    const float* x    = (const float*)d_in[0];
    const float* thr  = (const float*)d_in[1];
    const int*   ordv = (const int*)d_in[2];
    const float* wts  = (const float*)d_in[3];
    float*       out  = (float*)d_out;

    const size_t pk_bytes = (size_t)TT * 1024 * 4;       // 16 MB
    const size_t xt_bytes = (size_t)CC * 2048 * 4;       // 4 MB

    if (d_ws && ws_size >= pk_bytes + xt_bytes) {
        unsigned int* pkg = (unsigned int*)d_ws;
        unsigned int* xt  = (unsigned int*)((char*)d_ws + pk_bytes);
        pack_trees<<<TT, 256, 0, stream>>>(thr, ordv, pkg);
        dim3 gx(2048 / 32, CC / 32);
        pack_x<<<gx, 256, 0, stream>>>(x, xt);
        hipFuncSetAttribute((const void*)rhf_main,
                            hipFuncAttributeMaxDynamicSharedMemorySize, LDS_BYTES);
        rhf_main<<<2048, 512, LDS_BYTES, stream>>>(pkg, xt, wts, out);
    } else {
        hipFuncSetAttribute((const void*)rhf_fallback,
                            hipFuncAttributeMaxDynamicSharedMemorySize, F_LDS);
        rhf_fallback<<<F_NPANELS * (TT / F_TPB), 512, F_LDS, stream>>>(x, thr, ordv, wts, out);
    }
}

// Round 6
// 170.394 us; speedup vs baseline: 14.4897x; 1.1611x over previous
//
#include <hip/hip_runtime.h>
#include <hip/hip_fp16.h>

#define BB 4096
#define CC 512
#define TT 4096
#define NN 1023
#define NL 1024
#define DEPTH 10

// ===================== pre-kernels (write d_ws) =====================

// pk[t][0]=0; pk[t][1+j] = (ord<<16) | f16bits(thr)   (slot = node+1)
__global__ __launch_bounds__(256) void pack_trees(const float* __restrict__ thr,
                                                  const int* __restrict__ ord,
                                                  unsigned int* __restrict__ pk) {
    int t = blockIdx.x;
    const float* tr = thr + (size_t)t * NN;
    const int*   oo = ord + (size_t)t * NN;
    unsigned int* o = pk + ((size_t)t << 10);
    if (threadIdx.x == 0) o[0] = 0u;
    for (int j = threadIdx.x; j < NN; j += 256)
        o[1 + j] = ((unsigned int)oo[j] << 16) |
                   (unsigned int)__half_as_ushort(__float2half(tr[j]));
}

// xt[c*2048 + b2] = {lo: f16 x[b2][c], hi: f16 x[b2+2048][c]}  (b2 < 2048)
__global__ __launch_bounds__(256) void pack_x(const float* __restrict__ x,
                                              unsigned int* __restrict__ xt) {
    __shared__ float tA[32][33];
    __shared__ float tB[32][33];
    int tx = threadIdx.x & 31, ty = threadIdx.x >> 5;   // 32 x 8
    int b0 = blockIdx.x * 32;      // b2 tile
    int c0 = blockIdx.y * 32;      // c tile
    for (int i = ty; i < 32; i += 8) {
        tA[i][tx] = x[(size_t)(b0 + i) * CC + c0 + tx];
        tB[i][tx] = x[(size_t)(2048 + b0 + i) * CC + c0 + tx];
    }
    __syncthreads();
    for (int i = ty; i < 32; i += 8) {
        int c = c0 + i;
        unsigned int lo = __half_as_ushort(__float2half(tA[tx][i]));
        unsigned int hi = __half_as_ushort(__float2half(tB[tx][i]));
        xt[(size_t)c * 2048 + b0 + tx] = lo | (hi << 16);
    }
}

// ===================== main kernel =====================
// grid 2048, XCD-swizzled: xcd=i&7 -> tb = xcd*4 + (i>>3)/64, panel = (i>>3)&63
//   (each XCD's CUs share 4 tree-blocks = 2 MB of packed trees -> L2-resident)
// 512 threads = 8 waves; wave wv runs 4 chains/lane (4 trees) per group; 4 groups.
// Trees staged in LDS only for levels 0..7 (slots 1..255, 1 KiB/tree);
// levels 8,9 node-pairs read directly from global pk (L2).
// LDS (exactly 160 KiB):
//   xs2 u32[512][32]   @ 0     (64K)  {f16 x[b], f16 x[b+2048]}; gather bank = lane&31
//   pk  u32[8][2][1024]@ 64K   (64K)  per-wave dbuf: 4 trees x 256 slots
//   res u32[64][128]   @ 128K  (32K)  (leaf<<21)|(f32bits(|minm|)>>11), +r col swizzle
#define LDS_BYTES 163840

typedef __attribute__((address_space(1))) const void gv_t;
typedef __attribute__((address_space(3))) void lv_t;

__global__ __launch_bounds__(512, 1)
void rhf_main(const unsigned int* __restrict__ pkg,
              const unsigned int* __restrict__ xt,
              const float* __restrict__ wts,
              float* __restrict__ out) {
    extern __shared__ char smem[];
    unsigned int* xs2 = (unsigned int*)smem;
    unsigned int* pk  = (unsigned int*)(smem + 65536);
    unsigned int* res = (unsigned int*)(smem + 131072);

    const int tid   = threadIdx.x;
    const int lane  = tid & 63;
    const int wv    = tid >> 6;          // 0..7
    const int i     = blockIdx.x;
    const int tb    = ((i & 7) << 2) + ((i >> 3) >> 6);   // 0..31
    const int panel = (i >> 3) & 63;                      // 0..63

    // ---- per-wave tree DMA: 4 trees x 1 KiB (slots 0..255 = levels 0..7) ----
    const char* gbase = (const char*)(pkg + ((size_t)tb * 128) * 1024);
    auto dma = [&](int g, int buf) {
        const char* s = gbase + ((size_t)(g * 32 + wv * 4)) * 4096 + lane * 16;
        char* d = (char*)(pk + wv * 2048 + buf * 1024) + lane * 16;
        #pragma unroll
        for (int q = 0; q < 4; ++q)
            __builtin_amdgcn_global_load_lds((gv_t*)(s + q * 4096),
                                             (lv_t*)(d + q * 1024), 16, 0, 0);
    };

    dma(0, 0);

    // ---- stage xs2: coalesced uint4; LDS writes conflict-free ----
    {
        const unsigned int* src = xt + (size_t)panel * 32;
        #pragma unroll
        for (int k = 0; k < 8; ++k) {
            int i4 = k * 512 + tid;          // 4096 uint4 = 64KB
            int c  = i4 >> 3;
            int s0 = (i4 & 7) << 2;
            uint4 v = *(const uint4*)(src + (size_t)c * 2048 + s0);
            *(uint4*)(xs2 + (i4 << 2)) = v;
        }
    }
    __syncthreads();     // xs2 visible; own DMA(0) drained (barrier implies vmcnt(0))

    const int r   = lane;
    const int sfx = lane & 31;            // xs2 column (bank = sfx: conflict-free)
    const int hsh = (lane & 32) >> 1;     // 0 / 16 : which f16 half

    int cur = 0;
    #pragma unroll 1
    for (int g = 0; g < 4; ++g) {
        if (g < 3) dma(g + 1, cur ^ 1);   // fire-and-forget into alt buffer

        const unsigned int* pkt = pk + wv * 2048 + cur * 1024;          // 4 x 256
        const unsigned int* gt  = pkg + ((size_t)(tb * 128 + g * 32 + wv * 4)) * 1024;

        float amin[4];
        int   sl[4];
        unsigned int nd[4];
        #pragma unroll
        for (int c = 0; c < 4; ++c) {
            amin[c] = __builtin_inff();
            sl[c]   = 1;                        // slot = node+1, root at 1
            nd[c]   = pkt[c * 256 + 1];
        }

        #pragma unroll
        for (int d = 0; d < DEPTH; ++d) {
            uint2 ch[4];
            #pragma unroll
            for (int c = 0; c < 4; ++c) {
                if (d < 7)       ch[c] = *(const uint2*)(pkt + c * 256 + 2 * sl[c]);   // LDS
                else if (d < 9)  ch[c] = *(const uint2*)(gt + c * 1024 + 2 * sl[c]);   // L2
            }
            #pragma unroll
            for (int c = 0; c < 4; ++c) {
                float thv = __half2float(__ushort_as_half((unsigned short)(nd[c] & 0xffffu)));
                int   orv = (int)(nd[c] >> 16);
                unsigned int xw = xs2[(orv << 5) + sfx];                 // bank = sfx
                float feat = __half2float(__ushort_as_half((unsigned short)((xw >> hsh) & 0xffffu)));
                float m = feat - thv;
                amin[c] = fminf(amin[c], fabsf(m));
                int right = (m > 0.0f) ? 1 : 0;
                sl[c] = 2 * sl[c] + right;
                if (d < 9) nd[c] = right ? ch[c].y : ch[c].x;
            }
        }

        #pragma unroll
        for (int c = 0; c < 4; ++c) {
            int leaf = sl[c] - NL;
            unsigned int p = ((unsigned int)leaf << 21) | (__float_as_uint(amin[c]) >> 11);
            int col = g * 32 + wv * 4 + c;
            res[(r << 7) + ((col + r) & 127)] = p;      // 2-way (free)
        }

        if (g < 3) {
            asm volatile("s_waitcnt vmcnt(0)" ::: "memory");  // own DMA(g+1) landed
            __builtin_amdgcn_sched_barrier(0);
            cur ^= 1;
        }
    }
    __syncthreads();     // all res entries visible

    // ---- output: batched wts gather (16 independent loads) + coalesced stores ----
    #pragma unroll
    for (int k = 0; k < 16; ++k) {
        int idx = k * 512 + tid;
        int rr = idx >> 7;
        int c  = idx & 127;
        unsigned int p = res[(rr << 7) + ((c + rr) & 127)];
        int   leaf = (int)(p >> 21);
        float am   = __uint_as_float((p & 0x1FFFFFu) << 11);
        int   t    = tb * 128 + c;
        float w    = wts[(size_t)t * NL + leaf];
        size_t b = (rr < 32) ? ((size_t)panel * 32 + rr)
                             : ((size_t)2048 + (size_t)panel * 32 + (rr - 32));
        out[b * TT + t] = am * w;
    }
}

// ===================== fallback (round-4, proven 541us) =====================
#define F_SP 32
#define F_TG 16
#define F_GROUPS 8
#define F_TPB (F_TG * F_GROUPS)
#define F_NPANELS (BB / F_SP)
#define F_LDS 147456

__global__ __launch_bounds__(512, 1)
void rhf_fallback(const float* __restrict__ x, const float* __restrict__ thr_g,
                  const int* __restrict__ ord_g, const float* __restrict__ wts,
                  float* __restrict__ out) {
    extern __shared__ char smem[];
    float*        xs  = (float*)(smem);
    unsigned int* pk  = (unsigned int*)(smem + 65536);
    float*        res = (float*)(smem + 131072);
    const int tid = threadIdx.x, s = tid & 31, slot = tid >> 5;
    const int panel = blockIdx.x & (F_NPANELS - 1), tb = blockIdx.x >> 7;
    const float* xbase = x + (size_t)panel * F_SP * CC;
    #pragma unroll
    for (int k = 0; k < (F_SP * CC) / 512; ++k) {
        int idx = k * 512 + tid, r = idx >> 9, c = idx & 511;
        xs[(c << 5) + r] = xbase[r * CC + c];
    }
    float4 pthr[8]; int4 pord[8]; float tthr[3]; int tord[3];
    auto prefetch = [&](int g) {
        const size_t base = (size_t)(tb * F_TPB + g * F_TG + slot) * NN;
        #pragma unroll
        for (int k = 0; k < 8; ++k) {
            int j = k * 128 + 4 * s;
            if (j < 1020) { pthr[k] = *(const float4*)(thr_g + base + j);
                            pord[k] = *(const int4*)(ord_g + base + j); }
            else { tthr[0]=thr_g[base+1020]; tord[0]=ord_g[base+1020];
                   tthr[1]=thr_g[base+1021]; tord[1]=ord_g[base+1021];
                   tthr[2]=thr_g[base+1022]; tord[2]=ord_g[base+1022]; }
        }
    };
    auto pack1 = [](float f, int o) -> unsigned int {
        return ((unsigned int)o << 16) | (unsigned int)__half_as_ushort(__float2half(f));
    };
    auto commit = [&]() {
        unsigned int* pt = pk + (slot << 10);
        #pragma unroll
        for (int k = 0; k < 8; ++k) {
            int j = k * 128 + 4 * s;
            if (j < 1020) {
                pt[1+j+0]=pack1(pthr[k].x,pord[k].x); pt[1+j+1]=pack1(pthr[k].y,pord[k].y);
                pt[1+j+2]=pack1(pthr[k].z,pord[k].z); pt[1+j+3]=pack1(pthr[k].w,pord[k].w);
            } else { pt[1+1020]=pack1(tthr[0],tord[0]); pt[1+1021]=pack1(tthr[1],tord[1]);
                     pt[1+1022]=pack1(tthr[2],tord[2]); }
        }
    };
    prefetch(0);
    __builtin_amdgcn_sched_barrier(0);
    for (int g = 0; g < F_GROUPS; ++g) {
        __syncthreads();
        commit();
        __syncthreads();
        if (g + 1 < F_GROUPS) prefetch(g + 1);
        __builtin_amdgcn_sched_barrier(0);
        const int t = tb * F_TPB + g * F_TG + slot;
        const unsigned int* pkt = pk + (slot << 10);
        float minm = __builtin_inff();
        int sl = 1;
        unsigned int cur = pkt[1];
        #pragma unroll
        for (int d = 0; d < DEPTH; ++d) {
            uint2 ch;
            if (d < DEPTH - 1) ch = *(const uint2*)(pkt + 2 * sl);
            float thv = __half2float(__ushort_as_half((unsigned short)(cur & 0xffffu)));
            int orv = (int)(cur >> 16);
            float feat = xs[(orv << 5) + s];
            float m = feat - thv;
            bool take = fabsf(m) < fabsf(minm);
            minm = take ? m : minm;
            int right = (m > 0.0f) ? 1 : 0;
            sl = 2 * sl + right;
            if (d < DEPTH - 1) cur = right ? ch.y : ch.x;
        }
        int leaf = sl - NL;
        float w = wts[(size_t)t * NL + leaf];
        int col = g * F_TG + slot;
        res[(s << 7) + ((col + s) & 127)] = fabsf(minm) * w;
    }
    __syncthreads();
    float* obase = out + (size_t)panel * F_SP * TT + (size_t)tb * F_TPB;
    #pragma unroll
    for (int k = 0; k < (F_SP * F_TPB) / 512; ++k) {
        int idx = k * 512 + tid, rr = idx >> 7, c = idx & 127;
        obase[(size_t)rr * TT + c] = res[(rr << 7) + ((c + rr) & 127)];
    }
}

// ===================== launch =====================
extern "C" void kernel_launch(void* const* d_in, const int* in_sizes, int n_in,
                              void* d_out, int out_size, void* d_ws, size_t ws_size,
                              hipStream_t stream) {
    const float* x    = (const float*)d_in[0];
    const float* thr  = (const float*)d_in[1];
    const int*   ordv = (const int*)d_in[2];
    const float* wts  = (const float*)d_in[3];
    float*       out  = (float*)d_out;

    const size_t pk_bytes = (size_t)TT * 1024 * 4;       // 16 MB
    const size_t xt_bytes = (size_t)CC * 2048 * 4;       // 4 MB

    if (d_ws && ws_size >= pk_bytes + xt_bytes) {
        unsigned int* pkg = (unsigned int*)d_ws;
        unsigned int* xt  = (unsigned int*)((char*)d_ws + pk_bytes);
        pack_trees<<<TT, 256, 0, stream>>>(thr, ordv, pkg);
        dim3 gx(2048 / 32, CC / 32);
        pack_x<<<gx, 256, 0, stream>>>(x, xt);
        hipFuncSetAttribute((const void*)rhf_main,
                            hipFuncAttributeMaxDynamicSharedMemorySize, LDS_BYTES);
        rhf_main<<<2048, 512, LDS_BYTES, stream>>>(pkg, xt, wts, out);
    } else {
        hipFuncSetAttribute((const void*)rhf_fallback,
                            hipFuncAttributeMaxDynamicSharedMemorySize, F_LDS);
        rhf_fallback<<<F_NPANELS * (TT / F_TPB), 512, F_LDS, stream>>>(x, thr, ordv, wts, out);
    }
}

// Round 7
// 160.892 us; speedup vs baseline: 15.3455x; 1.0591x over previous
//
#include <hip/hip_runtime.h>
#include <hip/hip_fp16.h>

#define BB 4096
#define CC 512
#define TT 4096
#define NN 1023
#define NL 1024
#define DEPTH 10

// ===================== pre-kernels (write d_ws) =====================

__device__ __forceinline__ unsigned pack_node(float th, int o) {
    return ((unsigned)o << 16) | (unsigned)__half_as_ushort(__float2half(th));
}

// pk_lo[t][j] j=0..511: slot j -> node j-1 (depths 0..8); slot 0 = 0.
// tails[t][i] i=0..255 (depth-8 slot 256+i):
//   {ndL (slot 512+2i), ndR (slot 513+2i), w01, w23}  (leaves 4i..4i+3, f16)
__global__ __launch_bounds__(256)
void pack_trees(const float* __restrict__ thr, const int* __restrict__ ord,
                const float* __restrict__ wts,
                unsigned* __restrict__ pk_lo, uint4* __restrict__ tails) {
    int t = blockIdx.x, tid = threadIdx.x;
    const float* tr = thr + (size_t)t * NN;
    const int*   oo = ord + (size_t)t * NN;
    unsigned* plo = pk_lo + ((size_t)t << 9);
    #pragma unroll
    for (int k = 0; k < 2; ++k) {
        int j = k * 256 + tid;
        plo[j] = (j == 0) ? 0u : pack_node(tr[j - 1], oo[j - 1]);
    }
    int i = tid;
    int nL = 511 + 2 * i, nR = 512 + 2 * i;
    unsigned ndL = pack_node(tr[nL], oo[nL]);
    unsigned ndR = pack_node(tr[nR], oo[nR]);
    float4 w4 = *(const float4*)(wts + ((size_t)t << 10) + 4 * i);
    unsigned w01 = (unsigned)__half_as_ushort(__float2half(w4.x)) |
                   ((unsigned)__half_as_ushort(__float2half(w4.y)) << 16);
    unsigned w23 = (unsigned)__half_as_ushort(__float2half(w4.z)) |
                   ((unsigned)__half_as_ushort(__float2half(w4.w)) << 16);
    tails[((size_t)t << 8) + i] = make_uint4(ndL, ndR, w01, w23);
}

// xt[c*2048 + b2] = {lo: f16 x[b2][c], hi: f16 x[b2+2048][c]}
__global__ __launch_bounds__(256) void pack_x(const float* __restrict__ x,
                                              unsigned int* __restrict__ xt) {
    __shared__ float tA[32][33];
    __shared__ float tB[32][33];
    int tx = threadIdx.x & 31, ty = threadIdx.x >> 5;
    int b0 = blockIdx.x * 32;
    int c0 = blockIdx.y * 32;
    for (int i = ty; i < 32; i += 8) {
        tA[i][tx] = x[(size_t)(b0 + i) * CC + c0 + tx];
        tB[i][tx] = x[(size_t)(2048 + b0 + i) * CC + c0 + tx];
    }
    __syncthreads();
    for (int i = ty; i < 32; i += 8) {
        int c = c0 + i;
        unsigned lo = __half_as_ushort(__float2half(tA[tx][i]));
        unsigned hi = __half_as_ushort(__float2half(tB[tx][i]));
        xt[(size_t)c * 2048 + b0 + tx] = lo | (hi << 16);
    }
}

// ===================== main kernel =====================
// grid 2048, XCD-swizzled. 512 threads = 8 waves, 64 samples (lane), 4 chains/thread,
// 4 groups x 32 trees. Staged: depths 0..8 (512 slots, 2KB/tree), single-buffered
// per-wave (4 trees x 2KB x 8 waves = 64KB). Level 9 + weights from 16B tail records.
// LDS (160 KiB): xs2 64K @0 | trees 64K @64K | res f32[64][128] 32K @128K
#define LDS_BYTES 163840

typedef __attribute__((address_space(1))) const void gv_t;
typedef __attribute__((address_space(3))) void lv_t;

__global__ __launch_bounds__(512, 1)
void rhf_main(const unsigned* __restrict__ pk_lo, const uint4* __restrict__ tails,
              const unsigned* __restrict__ xt, float* __restrict__ out) {
    extern __shared__ char smem[];
    unsigned* xs2 = (unsigned*)smem;
    unsigned* trl = (unsigned*)(smem + 65536);
    float*    res = (float*)(smem + 131072);

    const int tid  = threadIdx.x;
    const int lane = tid & 63;
    const int wv   = tid >> 6;
    const int bi   = blockIdx.x;
    const int tb    = ((bi & 7) << 2) + ((bi >> 3) >> 6);   // 0..31
    const int panel = (bi >> 3) & 63;                       // 0..63

    // ---- per-wave tree DMA: 4 trees x 2KB contiguous = 8KB ----
    const char* gsrc0 = (const char*)pk_lo + ((size_t)(tb * 128) << 11);
    char* ldst = (char*)trl + wv * 8192 + lane * 16;
    auto dma = [&](int g) {
        const char* s = gsrc0 + ((size_t)(g * 32 + wv * 4) << 11) + lane * 16;
        #pragma unroll
        for (int q = 0; q < 8; ++q)
            __builtin_amdgcn_global_load_lds((gv_t*)(s + q * 1024),
                                             (lv_t*)(ldst + q * 1024), 16, 0, 0);
    };

    dma(0);

    // ---- stage xs2 (coalesced uint4, conflict-free LDS writes) ----
    {
        const unsigned* src = xt + (size_t)panel * 32;
        #pragma unroll
        for (int k = 0; k < 8; ++k) {
            int i4 = k * 512 + tid;
            int c = i4 >> 3, s0 = (i4 & 7) << 2;
            uint4 v = *(const uint4*)(src + (size_t)c * 2048 + s0);
            *(uint4*)(xs2 + (i4 << 2)) = v;
        }
    }
    __syncthreads();   // xs2 visible; DMA(0) drained (barrier drains vmcnt)

    const int sfx = lane & 31;            // xs2 bank = sfx: conflict-free
    const int hsh = (lane & 32) >> 1;     // f16 half select
    const int r   = lane;

    #pragma unroll 1
    for (int g = 0; g < 4; ++g) {
        if (g > 0) {
            asm volatile("s_waitcnt vmcnt(0)" ::: "memory");   // DMA(g) landed
            __builtin_amdgcn_sched_barrier(0);
        }
        const int t0 = tb * 128 + g * 32 + wv * 4;
        const unsigned* pkw = trl + wv * 2048;

        float amin[4]; int sl[4]; unsigned nd[4]; uint4 rec[4];
        #pragma unroll
        for (int c = 0; c < 4; ++c) {
            amin[c] = __builtin_inff(); sl[c] = 1; nd[c] = pkw[c * 512 + 1];
        }

        #pragma unroll
        for (int d = 0; d < 9; ++d) {
            uint2 ch[4];
            #pragma unroll
            for (int c = 0; c < 4; ++c) {
                if (d < 8) ch[c] = *(const uint2*)(pkw + c * 512 + 2 * sl[c]); // LDS
                else       rec[c] = tails[((size_t)(t0 + c) << 8) + (sl[c] - 256)]; // L2
            }
            #pragma unroll
            for (int c = 0; c < 4; ++c) {
                float thv = __half2float(__ushort_as_half((unsigned short)(nd[c] & 0xffffu)));
                int   orv = (int)(nd[c] >> 16);
                unsigned xw = xs2[(orv << 5) + sfx];
                float feat = __half2float(__ushort_as_half((unsigned short)((xw >> hsh) & 0xffffu)));
                float m = feat - thv;
                amin[c] = fminf(amin[c], fabsf(m));
                int right = (m > 0.0f) ? 1 : 0;
                sl[c] = 2 * sl[c] + right;
                if (d < 8) nd[c] = right ? ch[c].y : ch[c].x;
            }
        }

        if (g < 3) { dma(g + 1); __builtin_amdgcn_sched_barrier(0); }  // hide under tail

        // ---- tail: level 9 + fused weight ----
        #pragma unroll
        for (int c = 0; c < 4; ++c) {
            int right8 = sl[c] & 1;
            unsigned nd9 = right8 ? rec[c].y : rec[c].x;
            float thv = __half2float(__ushort_as_half((unsigned short)(nd9 & 0xffffu)));
            int   orv = (int)(nd9 >> 16);
            unsigned xw = xs2[(orv << 5) + sfx];
            float feat = __half2float(__ushort_as_half((unsigned short)((xw >> hsh) & 0xffffu)));
            float m = feat - thv;
            amin[c] = fminf(amin[c], fabsf(m));
            int right9 = (m > 0.0f) ? 1 : 0;
            unsigned wsel = right8 ? rec[c].w : rec[c].z;
            unsigned short wb = (unsigned short)(right9 ? (wsel >> 16) : (wsel & 0xffffu));
            float w = __half2float(__ushort_as_half(wb));
            int col = g * 32 + wv * 4 + c;
            res[(r << 7) + ((col + r) & 127)] = amin[c] * w;   // 2-way (free)
        }
    }
    __syncthreads();

    // ---- coalesced output ----
    float* obase = out + (size_t)(tb * 128);
    #pragma unroll
    for (int k = 0; k < 16; ++k) {
        int idx = k * 512 + tid;
        int rr = idx >> 7, cc = idx & 127;
        float v = res[(rr << 7) + ((cc + rr) & 127)];
        size_t b = (rr < 32) ? ((size_t)panel * 32 + rr)
                             : (2048 + (size_t)panel * 32 + (rr - 32));
        obase[b * TT + cc] = v;
    }
}

// ===================== fallback (round-4, proven 541us) =====================
#define F_SP 32
#define F_TG 16
#define F_GROUPS 8
#define F_TPB (F_TG * F_GROUPS)
#define F_NPANELS (BB / F_SP)
#define F_LDS 147456

__global__ __launch_bounds__(512, 1)
void rhf_fallback(const float* __restrict__ x, const float* __restrict__ thr_g,
                  const int* __restrict__ ord_g, const float* __restrict__ wts,
                  float* __restrict__ out) {
    extern __shared__ char smem[];
    float*        xs  = (float*)(smem);
    unsigned int* pk  = (unsigned int*)(smem + 65536);
    float*        res = (float*)(smem + 131072);
    const int tid = threadIdx.x, s = tid & 31, slot = tid >> 5;
    const int panel = blockIdx.x & (F_NPANELS - 1), tb = blockIdx.x >> 7;
    const float* xbase = x + (size_t)panel * F_SP * CC;
    #pragma unroll
    for (int k = 0; k < (F_SP * CC) / 512; ++k) {
        int idx = k * 512 + tid, r = idx >> 9, c = idx & 511;
        xs[(c << 5) + r] = xbase[r * CC + c];
    }
    float4 pthr[8]; int4 pord[8]; float tthr[3]; int tord[3];
    auto prefetch = [&](int g) {
        const size_t base = (size_t)(tb * F_TPB + g * F_TG + slot) * NN;
        #pragma unroll
        for (int k = 0; k < 8; ++k) {
            int j = k * 128 + 4 * s;
            if (j < 1020) { pthr[k] = *(const float4*)(thr_g + base + j);
                            pord[k] = *(const int4*)(ord_g + base + j); }
            else { tthr[0]=thr_g[base+1020]; tord[0]=ord_g[base+1020];
                   tthr[1]=thr_g[base+1021]; tord[1]=ord_g[base+1021];
                   tthr[2]=thr_g[base+1022]; tord[2]=ord_g[base+1022]; }
        }
    };
    auto pack1 = [](float f, int o) -> unsigned int {
        return ((unsigned int)o << 16) | (unsigned int)__half_as_ushort(__float2half(f));
    };
    auto commit = [&]() {
        unsigned int* pt = pk + (slot << 10);
        #pragma unroll
        for (int k = 0; k < 8; ++k) {
            int j = k * 128 + 4 * s;
            if (j < 1020) {
                pt[1+j+0]=pack1(pthr[k].x,pord[k].x); pt[1+j+1]=pack1(pthr[k].y,pord[k].y);
                pt[1+j+2]=pack1(pthr[k].z,pord[k].z); pt[1+j+3]=pack1(pthr[k].w,pord[k].w);
            } else { pt[1+1020]=pack1(tthr[0],tord[0]); pt[1+1021]=pack1(tthr[1],tord[1]);
                     pt[1+1022]=pack1(tthr[2],tord[2]); }
        }
    };
    prefetch(0);
    __builtin_amdgcn_sched_barrier(0);
    for (int g = 0; g < F_GROUPS; ++g) {
        __syncthreads();
        commit();
        __syncthreads();
        if (g + 1 < F_GROUPS) prefetch(g + 1);
        __builtin_amdgcn_sched_barrier(0);
        const int t = tb * F_TPB + g * F_TG + slot;
        const unsigned int* pkt = pk + (slot << 10);
        float minm = __builtin_inff();
        int sl = 1;
        unsigned int cur = pkt[1];
        #pragma unroll
        for (int d = 0; d < DEPTH; ++d) {
            uint2 ch;
            if (d < DEPTH - 1) ch = *(const uint2*)(pkt + 2 * sl);
            float thv = __half2float(__ushort_as_half((unsigned short)(cur & 0xffffu)));
            int orv = (int)(cur >> 16);
            float feat = xs[(orv << 5) + s];
            float m = feat - thv;
            bool take = fabsf(m) < fabsf(minm);
            minm = take ? m : minm;
            int right = (m > 0.0f) ? 1 : 0;
            sl = 2 * sl + right;
            if (d < DEPTH - 1) cur = right ? ch.y : ch.x;
        }
        int leaf = sl - NL;
        float w = wts[(size_t)t * NL + leaf];
        int col = g * F_TG + slot;
        res[(s << 7) + ((col + s) & 127)] = fabsf(minm) * w;
    }
    __syncthreads();
    float* obase = out + (size_t)panel * F_SP * TT + (size_t)tb * F_TPB;
    #pragma unroll
    for (int k = 0; k < (F_SP * F_TPB) / 512; ++k) {
        int idx = k * 512 + tid, rr = idx >> 7, c = idx & 127;
        obase[(size_t)rr * TT + c] = res[(rr << 7) + ((c + rr) & 127)];
    }
}

// ===================== launch =====================
extern "C" void kernel_launch(void* const* d_in, const int* in_sizes, int n_in,
                              void* d_out, int out_size, void* d_ws, size_t ws_size,
                              hipStream_t stream) {
    const float* x    = (const float*)d_in[0];
    const float* thr  = (const float*)d_in[1];
    const int*   ordv = (const int*)d_in[2];
    const float* wts  = (const float*)d_in[3];
    float*       out  = (float*)d_out;

    const size_t pk_bytes   = (size_t)TT * 512 * 4;    // 8 MB
    const size_t tail_bytes = (size_t)TT * 256 * 16;   // 16 MB
    const size_t xt_bytes   = (size_t)CC * 2048 * 4;   // 4 MB

    if (d_ws && ws_size >= pk_bytes + tail_bytes + xt_bytes) {
        unsigned* pk_lo = (unsigned*)d_ws;
        uint4*    tails = (uint4*)((char*)d_ws + pk_bytes);
        unsigned* xt    = (unsigned*)((char*)d_ws + pk_bytes + tail_bytes);
        pack_trees<<<TT, 256, 0, stream>>>(thr, ordv, wts, pk_lo, tails);
        dim3 gx(2048 / 32, CC / 32);
        pack_x<<<gx, 256, 0, stream>>>(x, xt);
        hipFuncSetAttribute((const void*)rhf_main,
                            hipFuncAttributeMaxDynamicSharedMemorySize, LDS_BYTES);
        rhf_main<<<2048, 512, LDS_BYTES, stream>>>(pk_lo, tails, xt, out);
    } else {
        hipFuncSetAttribute((const void*)rhf_fallback,
                            hipFuncAttributeMaxDynamicSharedMemorySize, F_LDS);
        rhf_fallback<<<F_NPANELS * (TT / F_TPB), 512, F_LDS, stream>>>(x, thr, ordv, wts, out);
    }
}

// Round 8
// 114.452 us; speedup vs baseline: 21.5720x; 1.4058x over previous
//
#include <hip/hip_runtime.h>
#include <hip/hip_fp16.h>

#define BB 4096
#define CC 512
#define TT 4096
#define NN 1023
#define NL 1024
#define DEPTH 10

// ===================== pre-kernels (write d_ws) =====================

__device__ __forceinline__ unsigned pack_node(float th, int o) {
    return ((unsigned)o << 16) | (unsigned)__half_as_ushort(__float2half(th));
}

// pk_lo[t][j] j=0..511: slot j -> node j-1 (depths 0..8); slot 0 = 0.
// tails[t][i] i=0..255 (depth-8 slot 256+i):
//   {ndL (slot 512+2i), ndR (slot 513+2i), w01, w23}  (leaves 4i..4i+3, f16)
__global__ __launch_bounds__(256)
void pack_trees(const float* __restrict__ thr, const int* __restrict__ ord,
                const float* __restrict__ wts,
                unsigned* __restrict__ pk_lo, uint4* __restrict__ tails) {
    int t = blockIdx.x, tid = threadIdx.x;
    const float* tr = thr + (size_t)t * NN;
    const int*   oo = ord + (size_t)t * NN;
    unsigned* plo = pk_lo + ((size_t)t << 9);
    #pragma unroll
    for (int k = 0; k < 2; ++k) {
        int j = k * 256 + tid;
        plo[j] = (j == 0) ? 0u : pack_node(tr[j - 1], oo[j - 1]);
    }
    int i = tid;
    int nL = 511 + 2 * i, nR = 512 + 2 * i;
    unsigned ndL = pack_node(tr[nL], oo[nL]);
    unsigned ndR = pack_node(tr[nR], oo[nR]);
    float4 w4 = *(const float4*)(wts + ((size_t)t << 10) + 4 * i);
    unsigned w01 = (unsigned)__half_as_ushort(__float2half(w4.x)) |
                   ((unsigned)__half_as_ushort(__float2half(w4.y)) << 16);
    unsigned w23 = (unsigned)__half_as_ushort(__float2half(w4.z)) |
                   ((unsigned)__half_as_ushort(__float2half(w4.w)) << 16);
    tails[((size_t)t << 8) + i] = make_uint4(ndL, ndR, w01, w23);
}

// xt16[c*4096 + b] = f16bits(x[b][c])  — f32 transpose via padded LDS tile
__global__ __launch_bounds__(256)
void pack_x16(const float* __restrict__ x, unsigned short* __restrict__ xt16) {
    __shared__ float tile[64][65];
    int tx = threadIdx.x & 63, ty = threadIdx.x >> 6;   // 64 x 4
    int b0 = blockIdx.x * 64;
    int c0 = blockIdx.y * 64;
    #pragma unroll
    for (int i = 0; i < 16; ++i) {
        int rr = i * 4 + ty;
        tile[rr][tx] = x[(size_t)(b0 + rr) * CC + c0 + tx];
    }
    __syncthreads();
    #pragma unroll
    for (int i = 0; i < 16; ++i) {
        int cr = i * 4 + ty;
        xt16[(size_t)(c0 + cr) * BB + b0 + tx] =
            __half_as_ushort(__float2half(tile[tx][cr]));   // bank = tx%32: clean
    }
}

// ===================== main kernel =====================
// grid 2048, XCD-swizzled. 1024 threads = 16 waves (4/SIMD), 64 samples (lane),
// 2 chains/thread, 4 groups x 32 trees (16 waves x 2). Staged: depths 0..8
// (512 slots, 2KB/tree) per-wave single-buffered. Level 9 + weights via 16B tails.
// LDS (160 KiB): xs16 u16[512][64] 64K @0 | trees 64K @64K | res f32[64][128] 32K @128K
#define LDS_BYTES 163840

typedef __attribute__((address_space(1))) const void gv_t;
typedef __attribute__((address_space(3))) void lv_t;

__global__ __launch_bounds__(1024, 1)
void rhf_main(const unsigned* __restrict__ pk_lo, const uint4* __restrict__ tails,
              const unsigned short* __restrict__ xt16, float* __restrict__ out) {
    extern __shared__ char smem[];
    unsigned short* xs16 = (unsigned short*)smem;
    unsigned*       trl  = (unsigned*)(smem + 65536);
    float*          res  = (float*)(smem + 131072);

    const int tid  = threadIdx.x;
    const int lane = tid & 63;
    const int wv   = tid >> 6;          // 0..15
    const int bi   = blockIdx.x;
    const int tb    = ((bi & 7) << 2) + ((bi >> 3) >> 6);   // 0..31
    const int panel = (bi >> 3) & 63;                       // 0..63

    // ---- per-wave tree DMA: 2 trees x 2KB = 4KB = 4 x (64 lanes x 16B) ----
    const char* gsrc0 = (const char*)pk_lo + ((size_t)(tb * 128) << 11);
    char* ldst = (char*)trl + wv * 4096 + lane * 16;
    auto dma = [&](int g) {
        const char* s = gsrc0 + ((size_t)(g * 32 + wv * 2) << 11) + lane * 16;
        #pragma unroll
        for (int q = 0; q < 4; ++q)
            __builtin_amdgcn_global_load_lds((gv_t*)(s + q * 1024),
                                             (lv_t*)(ldst + q * 1024), 16, 0, 0);
    };

    dma(0);

    // ---- stage xs16: 64KB; 8-thread clusters read 128B rows; linear LDS writes ----
    {
        const unsigned short* src = xt16 + (size_t)panel * 64;
        #pragma unroll
        for (int k = 0; k < 4; ++k) {
            int i4 = k * 1024 + tid;          // 0..4095 (16B units)
            int c  = i4 >> 3;
            int o8 = (i4 & 7) << 3;           // u16 offset in row
            uint4 v = *(const uint4*)(src + (size_t)c * BB + o8);
            *(uint4*)(xs16 + ((size_t)i4 << 3)) = v;
        }
    }
    __syncthreads();   // xs16 visible; DMA(0) drained (barrier drains vmcnt)

    #pragma unroll 1
    for (int g = 0; g < 4; ++g) {
        if (g > 0) {
            asm volatile("s_waitcnt vmcnt(0)" ::: "memory");   // DMA(g) landed
            __builtin_amdgcn_sched_barrier(0);
        }
        const int t0 = tb * 128 + g * 32 + wv * 2;
        const unsigned* pkw = trl + wv * 1024;

        float amin[2]; int sl[2]; unsigned nd[2]; uint4 rec[2];
        #pragma unroll
        for (int c = 0; c < 2; ++c) {
            amin[c] = __builtin_inff(); sl[c] = 1; nd[c] = pkw[c * 512 + 1];
        }

        #pragma unroll
        for (int d = 0; d < 9; ++d) {
            uint2 ch[2];
            #pragma unroll
            for (int c = 0; c < 2; ++c) {
                if (d < 8) ch[c] = *(const uint2*)(pkw + c * 512 + 2 * sl[c]); // LDS
                else       rec[c] = tails[((size_t)(t0 + c) << 8) + (sl[c] - 256)]; // L2
            }
            #pragma unroll
            for (int c = 0; c < 2; ++c) {
                float thv = __half2float(__ushort_as_half((unsigned short)(nd[c] & 0xffffu)));
                int   orv = (int)(nd[c] >> 16);
                float feat = __half2float(__ushort_as_half(xs16[(orv << 6) + lane]));
                float m = feat - thv;
                amin[c] = fminf(amin[c], fabsf(m));
                int right = (m > 0.0f) ? 1 : 0;
                sl[c] = 2 * sl[c] + right;
                if (d < 8) nd[c] = right ? ch[c].y : ch[c].x;
            }
        }

        if (g < 3) { dma(g + 1); __builtin_amdgcn_sched_barrier(0); }  // hide under tail

        // ---- tail: level 9 + fused weight ----
        #pragma unroll
        for (int c = 0; c < 2; ++c) {
            int right8 = sl[c] & 1;
            unsigned nd9 = right8 ? rec[c].y : rec[c].x;
            float thv = __half2float(__ushort_as_half((unsigned short)(nd9 & 0xffffu)));
            int   orv = (int)(nd9 >> 16);
            float feat = __half2float(__ushort_as_half(xs16[(orv << 6) + lane]));
            float m = feat - thv;
            amin[c] = fminf(amin[c], fabsf(m));
            int right9 = (m > 0.0f) ? 1 : 0;
            unsigned wsel = right8 ? rec[c].w : rec[c].z;
            unsigned short wb = (unsigned short)(right9 ? (wsel >> 16) : (wsel & 0xffffu));
            float w = __half2float(__ushort_as_half(wb));
            int col = g * 32 + wv * 2 + c;
            res[(lane << 7) + ((col + lane) & 127)] = amin[c] * w;   // 2-way (free)
        }
    }
    __syncthreads();

    // ---- coalesced output ----
    float* obase = out + (size_t)(tb * 128);
    #pragma unroll
    for (int k = 0; k < 8; ++k) {
        int idx = k * 1024 + tid;
        int rr = idx >> 7, cc = idx & 127;
        float v = res[(rr << 7) + ((cc + rr) & 127)];
        obase[((size_t)panel * 64 + rr) * TT + cc] = v;
    }
}

// ===================== fallback (round-4, proven 541us) =====================
#define F_SP 32
#define F_TG 16
#define F_GROUPS 8
#define F_TPB (F_TG * F_GROUPS)
#define F_NPANELS (BB / F_SP)
#define F_LDS 147456

__global__ __launch_bounds__(512, 1)
void rhf_fallback(const float* __restrict__ x, const float* __restrict__ thr_g,
                  const int* __restrict__ ord_g, const float* __restrict__ wts,
                  float* __restrict__ out) {
    extern __shared__ char smem[];
    float*        xs  = (float*)(smem);
    unsigned int* pk  = (unsigned int*)(smem + 65536);
    float*        res = (float*)(smem + 131072);
    const int tid = threadIdx.x, s = tid & 31, slot = tid >> 5;
    const int panel = blockIdx.x & (F_NPANELS - 1), tb = blockIdx.x >> 7;
    const float* xbase = x + (size_t)panel * F_SP * CC;
    #pragma unroll
    for (int k = 0; k < (F_SP * CC) / 512; ++k) {
        int idx = k * 512 + tid, r = idx >> 9, c = idx & 511;
        xs[(c << 5) + r] = xbase[r * CC + c];
    }
    float4 pthr[8]; int4 pord[8]; float tthr[3]; int tord[3];
    auto prefetch = [&](int g) {
        const size_t base = (size_t)(tb * F_TPB + g * F_TG + slot) * NN;
        #pragma unroll
        for (int k = 0; k < 8; ++k) {
            int j = k * 128 + 4 * s;
            if (j < 1020) { pthr[k] = *(const float4*)(thr_g + base + j);
                            pord[k] = *(const int4*)(ord_g + base + j); }
            else { tthr[0]=thr_g[base+1020]; tord[0]=ord_g[base+1020];
                   tthr[1]=thr_g[base+1021]; tord[1]=ord_g[base+1021];
                   tthr[2]=thr_g[base+1022]; tord[2]=ord_g[base+1022]; }
        }
    };
    auto pack1 = [](float f, int o) -> unsigned int {
        return ((unsigned int)o << 16) | (unsigned int)__half_as_ushort(__float2half(f));
    };
    auto commit = [&]() {
        unsigned int* pt = pk + (slot << 10);
        #pragma unroll
        for (int k = 0; k < 8; ++k) {
            int j = k * 128 + 4 * s;
            if (j < 1020) {
                pt[1+j+0]=pack1(pthr[k].x,pord[k].x); pt[1+j+1]=pack1(pthr[k].y,pord[k].y);
                pt[1+j+2]=pack1(pthr[k].z,pord[k].z); pt[1+j+3]=pack1(pthr[k].w,pord[k].w);
            } else { pt[1+1020]=pack1(tthr[0],tord[0]); pt[1+1021]=pack1(tthr[1],tord[1]);
                     pt[1+1022]=pack1(tthr[2],tord[2]); }
        }
    };
    prefetch(0);
    __builtin_amdgcn_sched_barrier(0);
    for (int g = 0; g < F_GROUPS; ++g) {
        __syncthreads();
        commit();
        __syncthreads();
        if (g + 1 < F_GROUPS) prefetch(g + 1);
        __builtin_amdgcn_sched_barrier(0);
        const int t = tb * F_TPB + g * F_TG + slot;
        const unsigned int* pkt = pk + (slot << 10);
        float minm = __builtin_inff();
        int sl = 1;
        unsigned int cur = pkt[1];
        #pragma unroll
        for (int d = 0; d < DEPTH; ++d) {
            uint2 ch;
            if (d < DEPTH - 1) ch = *(const uint2*)(pkt + 2 * sl);
            float thv = __half2float(__ushort_as_half((unsigned short)(cur & 0xffffu)));
            int orv = (int)(cur >> 16);
            float feat = xs[(orv << 5) + s];
            float m = feat - thv;
            bool take = fabsf(m) < fabsf(minm);
            minm = take ? m : minm;
            int right = (m > 0.0f) ? 1 : 0;
            sl = 2 * sl + right;
            if (d < DEPTH - 1) cur = right ? ch.y : ch.x;
        }
        int leaf = sl - NL;
        float w = wts[(size_t)t * NL + leaf];
        int col = g * F_TG + slot;
        res[(s << 7) + ((col + s) & 127)] = fabsf(minm) * w;
    }
    __syncthreads();
    float* obase = out + (size_t)panel * F_SP * TT + (size_t)tb * F_TPB;
    #pragma unroll
    for (int k = 0; k < (F_SP * F_TPB) / 512; ++k) {
        int idx = k * 512 + tid, rr = idx >> 7, c = idx & 127;
        obase[(size_t)rr * TT + c] = res[(rr << 7) + ((c + rr) & 127)];
    }
}

// ===================== launch =====================
extern "C" void kernel_launch(void* const* d_in, const int* in_sizes, int n_in,
                              void* d_out, int out_size, void* d_ws, size_t ws_size,
                              hipStream_t stream) {
    const float* x    = (const float*)d_in[0];
    const float* thr  = (const float*)d_in[1];
    const int*   ordv = (const int*)d_in[2];
    const float* wts  = (const float*)d_in[3];
    float*       out  = (float*)d_out;

    const size_t pk_bytes   = (size_t)TT * 512 * 4;    // 8 MB
    const size_t tail_bytes = (size_t)TT * 256 * 16;   // 16 MB
    const size_t xt_bytes   = (size_t)CC * BB * 2;     // 4 MB

    if (d_ws && ws_size >= pk_bytes + tail_bytes + xt_bytes) {
        unsigned*       pk_lo = (unsigned*)d_ws;
        uint4*          tails = (uint4*)((char*)d_ws + pk_bytes);
        unsigned short* xt16  = (unsigned short*)((char*)d_ws + pk_bytes + tail_bytes);
        pack_trees<<<TT, 256, 0, stream>>>(thr, ordv, wts, pk_lo, tails);
        dim3 gx(BB / 64, CC / 64);
        pack_x16<<<gx, 256, 0, stream>>>(x, xt16);
        hipFuncSetAttribute((const void*)rhf_main,
                            hipFuncAttributeMaxDynamicSharedMemorySize, LDS_BYTES);
        rhf_main<<<2048, 1024, LDS_BYTES, stream>>>(pk_lo, tails, xt16, out);
    } else {
        hipFuncSetAttribute((const void*)rhf_fallback,
                            hipFuncAttributeMaxDynamicSharedMemorySize, F_LDS);
        rhf_fallback<<<F_NPANELS * (TT / F_TPB), 512, F_LDS, stream>>>(x, thr, ordv, wts, out);
    }
}